// Round 8
// baseline (217.707 us; speedup 1.0000x reference)
//
#include <hip/hip_runtime.h>
#include <hip/hip_bf16.h>
#include <cstdint>

// GQA prefill: b=2, t=1024, E=2048, NQ=32, NKV=8, HD=64. fp32 in/out, bf16 MFMA inside.
//
// PANEL-MAJOR layout for all LDS-staged operands: [blk64 = idx/64][panel = k/8][64][8].
// One global_load_lds = one 1KB panel (contiguous global); fragment ds_read_b128 =
// panel*1024B + row*16B -> 2-way bank aliasing (free, m136) instead of 8-way.

typedef __attribute__((ext_vector_type(8))) short short8;   // 8 bf16 (MFMA A/B frag)
typedef __attribute__((ext_vector_type(4))) short short4v;
typedef __attribute__((ext_vector_type(4))) float f32x4;    // MFMA C/D frag

__device__ inline short f2b(float f) {  // fp32 -> bf16 (RNE)
  union { float f; unsigned u; } v; v.f = f;
  unsigned r = v.u + 0x7fffu + ((v.u >> 16) & 1u);
  return (short)(r >> 16);
}

__device__ inline float exp2_fast(float x) {
  float r;
  asm("v_exp_f32 %0, %1" : "=v"(r) : "v"(x));
  return r;
}

__device__ inline void gl_lds16(const void* g, void* l) {
  // async global->LDS, 16B/lane; LDS dest = wave-uniform base + lane*16
  __builtin_amdgcn_global_load_lds((const __attribute__((address_space(1))) void*)g,
                                   (__attribute__((address_space(3))) void*)l,
                                   16, 0, 0);
}

// ---------------- prep: x cast + all weight transposes in ONE launch ----------------
// bx < nCast: cast 1024 floats/block into panel-major xb. Else: 64x64 transpose tiles.
__global__ void prep_kernel(const float* __restrict__ x,
                            const float* __restrict__ wq, const float* __restrict__ wk,
                            const float* __restrict__ wv, const float* __restrict__ wo,
                            short* __restrict__ xb, short* __restrict__ WqkvT,
                            short* __restrict__ woT, int nCast) {
  const int bx = blockIdx.x;
  const int tid = threadIdx.x;
  if (bx < nCast) {
    int i = bx * 256 + tid;              // float4 index
    float4 v = ((const float4*)x)[i];
    int f0 = i * 4;
    int row = f0 >> 11, k = f0 & 2047;
    short4v o; o.x = f2b(v.x); o.y = f2b(v.y); o.z = f2b(v.z); o.w = f2b(v.w);
    size_t addr = ((size_t)(row >> 6) * 256 + (k >> 3)) * 512 + (row & 63) * 8 + (k & 7);
    *(short4v*)(xb + addr) = o;
    return;
  }
  __shared__ float tile[64][65];
  const int id = bx - nCast;
  const int wx = id % 80, ky = id / 80;
  const float* W; short* WT; int N, off, nb;
  if (wx < 32)      { W = wq; WT = WqkvT; N = 2048; off = 0;    nb = wx * 64; }
  else if (wx < 40) { W = wk; WT = WqkvT; N = 512;  off = 2048; nb = (wx - 32) * 64; }
  else if (wx < 48) { W = wv; WT = WqkvT; N = 512;  off = 2560; nb = (wx - 40) * 64; }
  else              { W = wo; WT = woT;   N = 2048; off = 0;    nb = (wx - 48) * 64; }
  const int kb = ky * 64;
  const int c = tid & 63, r0 = tid >> 6;
#pragma unroll
  for (int s = 0; s < 16; ++s) {
    int k = r0 + s * 4;
    tile[c][k] = W[(size_t)(kb + k) * N + nb + c];
  }
  __syncthreads();
#pragma unroll
  for (int s = 0; s < 16; ++s) {
    int n_abs = off + nb + r0 + s * 4;
    int k = kb + c;
    WT[((size_t)(n_abs >> 6) * 256 + (k >> 3)) * 512 + (n_abs & 63) * 8 + (k & 7)] =
        f2b(tile[r0 + s * 4][c]);
  }
}

// ---------------- shared K-loop: 128(M)x64(N), K=2048, BK=64, dbuf, panel-major ----------
// lA: 2 bufs x 16 panels (2 rb x 8 kq); lB: 2 bufs x 8 panels. 6 gl_lds16/wave/stage.
__device__ __forceinline__ void gemm_loop_bk64(const short* __restrict__ Ag0,
                                               const short* __restrict__ Bg0,
                                               short* lA, short* lB,
                                               int w, int lane, int l15, int q4,
                                               f32x4 acc[2][4]) {
  const int NS = 32;
  auto stage = [&](int s, int d) {
#pragma unroll
    for (int c = 0; c < 4; ++c) {
      int p = w * 4 + c;  // rb = p>>3, kq = p&7
      const short* src = Ag0 + ((size_t)(p >> 3) * 256 + s * 8 + (p & 7)) * 512 + lane * 8;
      gl_lds16(src, lA + d * 8192 + p * 512);
    }
#pragma unroll
    for (int c = 0; c < 2; ++c) {
      int q = w * 2 + c;
      const short* src = Bg0 + (size_t)(s * 8 + q) * 512 + lane * 8;
      gl_lds16(src, lB + d * 4096 + q * 512);
    }
  };
  stage(0, 0);
  const int rb = w >> 1;
  const int r64 = (w & 1) * 32;
  for (int s = 0; s < NS; ++s) {
    const int d = s & 1;
    __syncthreads();                     // drains stage(s) loads
    if (s + 1 < NS) stage(s + 1, d ^ 1); // prefetch ages one compute phase
#pragma unroll
    for (int ks = 0; ks < 2; ++ks) {
      const short* ap = lA + d * 8192 + (rb * 8 + ks * 4 + q4) * 512 + (r64 + l15) * 8;
      const short* bp = lB + d * 4096 + (ks * 4 + q4) * 512 + l15 * 8;
      short8 af[2], bf[4];
#pragma unroll
      for (int mf = 0; mf < 2; ++mf) af[mf] = *(const short8*)(ap + mf * 128);
#pragma unroll
      for (int nf = 0; nf < 4; ++nf) bf[nf] = *(const short8*)(bp + nf * 128);
#pragma unroll
      for (int mf = 0; mf < 2; ++mf)
#pragma unroll
        for (int nf = 0; nf < 4; ++nf)
          acc[mf][nf] = __builtin_amdgcn_mfma_f32_16x16x32_bf16(af[mf], bf[nf], acc[mf][nf], 0, 0, 0);
    }
  }
}

// ---------------- fused QKV GEMM + bias + RoPE + scatter epilogue ----------------
__launch_bounds__(256, 3)
__global__ void gemm_qkv(const short* __restrict__ A, const short* __restrict__ BT,
                         const float* __restrict__ bq, const float* __restrict__ bk,
                         const float* __restrict__ bv,
                         short* __restrict__ Qb, short* __restrict__ Kb,
                         short* __restrict__ VTb) {
  __shared__ __align__(16) short lA[16384];
  __shared__ __align__(16) short lB[8192];
  const int tid = threadIdx.x, lane = tid & 63, w = tid >> 6;
  const int q4 = lane >> 4, l15 = lane & 15;
  const int bn = blockIdx.x * 64, bm = blockIdx.y * 128;

  const short* Ag0 = A + (size_t)(bm >> 6) * 131072;
  const short* Bg0 = BT + (size_t)(bn >> 6) * 131072;

  f32x4 acc[2][4];
  const f32x4 fz = {0.f, 0.f, 0.f, 0.f};
#pragma unroll
  for (int i = 0; i < 2; ++i)
#pragma unroll
    for (int j = 0; j < 4; ++j) acc[i][j] = fz;

  gemm_loop_bk64(Ag0, Bg0, lA, lB, w, lane, l15, q4, acc);

  // ----- epilogue -----
  const float L2T = 0.4152410118609203f;          // log2(10000)/32
  const float theta_a = exp2_fast(-(float)l15 * L2T);
  const float theta_b = exp2_fast(-(float)(l15 + 16) * L2T);
  const float s2 = 0.18033688011112042f;          // 0.125 * log2(e): base-2 attn scores

  if (bn < 2048) {            // ---- Q: rope + scale -> Qb (b,h,t,64) row-major
    const int h = bn >> 6;
    float bb0 = bq[bn + l15], bb1 = bq[bn + 16 + l15], bb2 = bq[bn + 32 + l15], bb3 = bq[bn + 48 + l15];
#pragma unroll
    for (int mf = 0; mf < 2; ++mf)
#pragma unroll
      for (int r = 0; r < 4; ++r) {
        int row = bm + w * 32 + mf * 16 + q4 * 4 + r;
        int batch = row >> 10, t = row & 1023;
        float pos = (float)(t + 1);
        float sa, ca, sb, cb;
        __sincosf(pos * theta_a, &sa, &ca);
        __sincosf(pos * theta_b, &sb, &cb);
        float x0 = acc[mf][0][r] + bb0, x2 = acc[mf][2][r] + bb2;
        float x1 = acc[mf][1][r] + bb1, x3 = acc[mf][3][r] + bb3;
        size_t base = ((size_t)(batch * 32 + h) * 1024 + t) * 64;
        Qb[base + l15]      = f2b((x0 * ca - x2 * sa) * s2);
        Qb[base + l15 + 32] = f2b((x2 * ca + x0 * sa) * s2);
        Qb[base + l15 + 16] = f2b((x1 * cb - x3 * sb) * s2);
        Qb[base + l15 + 48] = f2b((x3 * cb + x1 * sb) * s2);
      }
  } else if (bn < 2560) {     // ---- K: rope -> Kb panels (b,hkv)[dq 8][t 1024][8]
    const int co = bn - 2048;
    const int hkv = co >> 6;
    float bb0 = bk[co + l15], bb1 = bk[co + 16 + l15], bb2 = bk[co + 32 + l15], bb3 = bk[co + 48 + l15];
    const int dq0 = l15 >> 3, j = l15 & 7;
#pragma unroll
    for (int mf = 0; mf < 2; ++mf)
#pragma unroll
      for (int r = 0; r < 4; ++r) {
        int row = bm + w * 32 + mf * 16 + q4 * 4 + r;
        int batch = row >> 10, t = row & 1023;
        float pos = (float)(t + 1);
        float sa, ca, sb, cb;
        __sincosf(pos * theta_a, &sa, &ca);
        __sincosf(pos * theta_b, &sb, &cb);
        float x0 = acc[mf][0][r] + bb0, x2 = acc[mf][2][r] + bb2;
        float x1 = acc[mf][1][r] + bb1, x3 = acc[mf][3][r] + bb3;
        size_t base = (size_t)(batch * 8 + hkv) * 65536 + (size_t)t * 8 + j;
        Kb[base + (size_t)(dq0)     * 8192] = f2b(x0 * ca - x2 * sa);  // d = l15
        Kb[base + (size_t)(dq0 + 2) * 8192] = f2b(x1 * cb - x3 * sb);  // d = l15+16
        Kb[base + (size_t)(dq0 + 4) * 8192] = f2b(x2 * ca + x0 * sa);  // d = l15+32
        Kb[base + (size_t)(dq0 + 6) * 8192] = f2b(x3 * cb + x1 * sb);  // d = l15+48
      }
  } else {                    // ---- V: bias -> VTb panels (b,hkv)[tq 128][d 64][8]
    const int co = bn - 2560;
    const int hkv = co >> 6;
    float bb[4];
#pragma unroll
    for (int nf = 0; nf < 4; ++nf) bb[nf] = bv[co + nf * 16 + l15];
#pragma unroll
    for (int mf = 0; mf < 2; ++mf) {
      int row0 = bm + w * 32 + mf * 16 + q4 * 4;
      int batch = row0 >> 10, t0 = row0 & 1023;
      size_t base = (size_t)(batch * 8 + hkv) * 65536 + ((size_t)(t0 >> 3) * 64) * 8 + (t0 & 7);
#pragma unroll
      for (int nf = 0; nf < 4; ++nf) {
        int d = nf * 16 + l15;
        short4v pk;
#pragma unroll
        for (int r = 0; r < 4; ++r) pk[r] = f2b(acc[mf][nf][r] + bb[nf]);
        *(short4v*)(VTb + base + d * 8) = pk;
      }
    }
  }
}

// ---------------- flash attention: 64-k stages, dbuf prefetch, panel-major K/V ----------
// grid (8, 32, B); block = 128 q-rows; wave w owns rows [qt*128+w*32, +32).
// Fixed-shift softmax P = 2^(s2-16): linear state, no running max.
#define PROW 72
__launch_bounds__(256, 3)
__global__ void attn6_kernel(const short* __restrict__ Qb, const short* __restrict__ Kb,
                             const short* __restrict__ VTb, short* __restrict__ AO) {
  __shared__ __align__(16) short lK[2][4096];   // [buf][dq 8][64 t][8]
  __shared__ __align__(16) short lV[2][4096];   // [buf][tq 8][64 d][8]
  __shared__ __align__(16) short lP[4][16 * PROW];
  const int tid = threadIdx.x, lane = tid & 63, w = tid >> 6;
  const int q4 = lane >> 4, l15 = lane & 15;
  const int qt = (int)gridDim.x - 1 - (int)blockIdx.x;  // heavy blocks first
  const int h = blockIdx.y, b = blockIdx.z;
  const int hkv = h >> 2;
  const int qb = qt * 128 + w * 32;
  const int kdiag = qb >> 6;            // wave's diagonal 64-tile index
  const int ns = qt * 2 + 2;            // 64-k stages (uniform in block)

  const short* Qg = Qb + (size_t)(b * 32 + h) * 65536;
  const short* Kg = Kb + (size_t)(b * 8 + hkv) * 65536;
  const short* Vg = VTb + (size_t)(b * 8 + hkv) * 65536;
  short* lPw = lP[w];

  short8 qf[2][2];
#pragma unroll
  for (int mf = 0; mf < 2; ++mf) {
    const short* qr = Qg + (size_t)(qb + mf * 16 + l15) * 64 + q4 * 8;
    qf[mf][0] = *(const short8*)(qr);
    qf[mf][1] = *(const short8*)(qr + 32);
  }

  const f32x4 fz = {0.f, 0.f, 0.f, 0.f};
  f32x4 o[2][4], ol[2];
#pragma unroll
  for (int mf = 0; mf < 2; ++mf) {
    ol[mf] = fz;
#pragma unroll
    for (int i = 0; i < 4; ++i) o[mf][i] = fz;
  }
  short8 ones;
#pragma unroll
  for (int i = 0; i < 8; ++i) ones[i] = (short)0x3F80;

  // wave w stages panels j = w*4..w*4+3: j<8 -> K panel dq=j; else V panel tq=j-8
  auto stage = [&](int s, int d) {
#pragma unroll
    for (int c = 0; c < 4; ++c) {
      int j = w * 4 + c;
      if (j < 8) {
        const short* src = Kg + ((size_t)j * 1024 + s * 64 + lane) * 8;
        gl_lds16(src, &lK[d][j * 512]);
      } else {
        int tq = j - 8;
        const short* src = Vg + ((size_t)(s * 8 + tq) * 64 + lane) * 8;
        gl_lds16(src, &lV[d][tq * 512]);
      }
    }
  };

  stage(0, 0);
  for (int s = 0; s < ns; ++s) {
    const int d = s & 1;
    __syncthreads();
    if (s + 1 < ns) stage(s + 1, d ^ 1);
    if (s <= kdiag) {
      short8 kf0[4], kf1[4], vf0[4], vf1[4];
#pragma unroll
      for (int nt = 0; nt < 4; ++nt) {
        kf0[nt] = *(const short8*)(&lK[d][q4 * 512 + (nt * 16 + l15) * 8]);
        kf1[nt] = *(const short8*)(&lK[d][(4 + q4) * 512 + (nt * 16 + l15) * 8]);
        vf0[nt] = *(const short8*)(&lV[d][q4 * 512 + (nt * 16 + l15) * 8]);
        vf1[nt] = *(const short8*)(&lV[d][(4 + q4) * 512 + (nt * 16 + l15) * 8]);
      }
      const bool diag = (s == kdiag);
#pragma unroll
      for (int mf = 0; mf < 2; ++mf) {
        f32x4 sv[4];
#pragma unroll
        for (int nt = 0; nt < 4; ++nt) {
          f32x4 z = __builtin_amdgcn_mfma_f32_16x16x32_bf16(qf[mf][0], kf0[nt], fz, 0, 0, 0);
          sv[nt] = __builtin_amdgcn_mfma_f32_16x16x32_bf16(qf[mf][1], kf1[nt], z, 0, 0, 0);
        }
        if (diag) {
#pragma unroll
          for (int r = 0; r < 4; ++r) {
            const int qrow = qb + mf * 16 + q4 * 4 + r;
            const int col = s * 64 + l15;
#pragma unroll
            for (int nt = 0; nt < 4; ++nt)
              if (col + nt * 16 > qrow) sv[nt][r] = -1e30f;
          }
        }
#pragma unroll
        for (int r = 0; r < 4; ++r)
#pragma unroll
          for (int nt = 0; nt < 4; ++nt)
            lPw[(q4 * 4 + r) * PROW + nt * 16 + l15] = f2b(exp2_fast(sv[nt][r] - 16.f));

        short8 pf0 = *(const short8*)(lPw + l15 * PROW + q4 * 8);
        short8 pf1 = *(const short8*)(lPw + l15 * PROW + 32 + q4 * 8);
        ol[mf] = __builtin_amdgcn_mfma_f32_16x16x32_bf16(pf0, ones, ol[mf], 0, 0, 0);
        ol[mf] = __builtin_amdgcn_mfma_f32_16x16x32_bf16(pf1, ones, ol[mf], 0, 0, 0);
#pragma unroll
        for (int dt = 0; dt < 4; ++dt) {
          o[mf][dt] = __builtin_amdgcn_mfma_f32_16x16x32_bf16(pf0, vf0[dt], o[mf][dt], 0, 0, 0);
          o[mf][dt] = __builtin_amdgcn_mfma_f32_16x16x32_bf16(pf1, vf1[dt], o[mf][dt], 0, 0, 0);
        }
      }
    }
  }

  // epilogue -> AO panel-major [rb][kq 256][64][8] for gemm_out's A operand
#pragma unroll
  for (int mf = 0; mf < 2; ++mf)
#pragma unroll
    for (int r = 0; r < 4; ++r) {
      float inv = __builtin_amdgcn_rcpf(ol[mf][r]);
      int row = b * 1024 + qb + mf * 16 + q4 * 4 + r;
#pragma unroll
      for (int dt = 0; dt < 4; ++dt) {
        int col = h * 64 + dt * 16 + l15;
        AO[((size_t)(row >> 6) * 256 + (col >> 3)) * 512 + (row & 63) * 8 + (col & 7)] =
            f2b(o[mf][dt][r] * inv);
      }
    }
}

// ---------------- output projection: BK=64 dbuf, panel-major, fp32 out + bias ----------
__launch_bounds__(256, 3)
__global__ void gemm_out(const short* __restrict__ A, const short* __restrict__ BT,
                         float* __restrict__ C, const float* __restrict__ bias,
                         int N, int K) {
  __shared__ __align__(16) short lA[16384];
  __shared__ __align__(16) short lB[8192];
  const int tid = threadIdx.x, lane = tid & 63, w = tid >> 6;
  const int q4 = lane >> 4, l15 = lane & 15;
  const int bn = blockIdx.x * 64, bm = blockIdx.y * 128;

  const short* Ag0 = A + (size_t)(bm >> 6) * 131072;
  const short* Bg0 = BT + (size_t)(bn >> 6) * 131072;

  f32x4 acc[2][4];
  const f32x4 fz = {0.f, 0.f, 0.f, 0.f};
#pragma unroll
  for (int i = 0; i < 2; ++i)
#pragma unroll
    for (int j = 0; j < 4; ++j) acc[i][j] = fz;

  gemm_loop_bk64(Ag0, Bg0, lA, lB, w, lane, l15, q4, acc);

#pragma unroll
  for (int mf = 0; mf < 2; ++mf)
#pragma unroll
    for (int nf = 0; nf < 4; ++nf) {
      int col = bn + nf * 16 + l15;
      float bb = bias[col];
#pragma unroll
      for (int r = 0; r < 4; ++r) {
        int row = bm + w * 32 + mf * 16 + q4 * 4 + r;
        C[(size_t)row * N + col] = acc[mf][nf][r] + bb;
      }
    }
}

extern "C" void kernel_launch(void* const* d_in, const int* in_sizes, int n_in,
                              void* d_out, int out_size, void* d_ws, size_t ws_size,
                              hipStream_t stream) {
  const float* x  = (const float*)d_in[0];
  const float* wq = (const float*)d_in[1];
  const float* bq = (const float*)d_in[2];
  const float* wk = (const float*)d_in[3];
  const float* bk = (const float*)d_in[4];
  const float* wv = (const float*)d_in[5];
  const float* bv = (const float*)d_in[6];
  const float* wo = (const float*)d_in[7];
  const float* bo = (const float*)d_in[8];
  float* out = (float*)d_out;
  const int B = in_sizes[0] / (1024 * 2048);
  const int M = B * 1024;

  char* ws = (char*)d_ws;
  size_t off = 0;
  auto alloc = [&](size_t bytes) -> char* {
    char* p = ws + off;
    off += (bytes + 255) & ~(size_t)255;
    return p;
  };
  short* xb    = (short*)alloc((size_t)M * 2048 * 2);              // panel-major A
  short* WqkvT = (short*)alloc((size_t)3072 * 2048 * 2);           // panel-major B (q|k|v)
  short* woT   = (short*)alloc((size_t)2048 * 2048 * 2);           // panel-major B
  short* Qb    = (short*)alloc((size_t)B * 32 * 1024 * 64 * 2);    // (b,h,t,d) row-major
  short* Kb    = (short*)alloc((size_t)B * 8 * 8 * 1024 * 8 * 2);  // (b,hkv)[dq][t][8]
  short* VTb   = (short*)alloc((size_t)B * 8 * 128 * 64 * 8 * 2);  // (b,hkv)[tq][d][8]
  short* AO    = (short*)alloc((size_t)M * 2048 * 2);              // panel-major A
  const int nCast = M * 2048 / 1024;  // cast blocks (1024 floats each)
  prep_kernel<<<nCast + 80 * 32, 256, 0, stream>>>(x, wq, wk, wv, wo, xb, WqkvT, woT, nCast);
  gemm_qkv<<<dim3(48, M / 128), 256, 0, stream>>>(xb, WqkvT, bq, bk, bv, Qb, Kb, VTb);
  attn6_kernel<<<dim3(8, 32, B), 256, 0, stream>>>(Qb, Kb, VTb, AO);
  gemm_out<<<dim3(32, M / 128), 256, 0, stream>>>(AO, woT, out, bo, 2048, 2048);
}